// Round 1
// baseline (1539.287 us; speedup 1.0000x reference)
//
#include <hip/hip_runtime.h>
#include <hip/hip_bf16.h>
#include <math.h>

#define BB 64
#define NN 4096
#define FF 256
#define DD 256
#define SS 8
#define HH 512
#define CPB 12                 // attention blocks per batch -> grid 768 = 3 blocks/CU exactly
#define NBLK (BB*CPB)
#define EPSV 1e-8f

// ---------------- wave reduction helpers ----------------
template<int CTRL>
__device__ __forceinline__ float dppAdd(float v) {
    int moved = __builtin_amdgcn_update_dpp(0, __float_as_int(v), CTRL, 0xF, 0xF, true);
    return v + __int_as_float(moved);
}
// full 64-lane all-reduce sum: DPP for xor1/2/4/8 (VALU pipe), shfl for 16/32
__device__ __forceinline__ float waveAllSum(float v) {
    v = dppAdd<0xB1>(v);    // quad_perm [1,0,3,2]  == xor 1
    v = dppAdd<0x4E>(v);    // quad_perm [2,3,0,1]  == xor 2
    v = dppAdd<0x141>(v);   // row_half_mirror      == xor-4-equivalent pairing
    v = dppAdd<0x140>(v);   // row_mirror           == xor-8-equivalent pairing
    v += __shfl_xor(v, 16);
    v += __shfl_xor(v, 32);
    return v;
}

// ---------------- K0: M = scale * Wq^T @ Wk  [D(j) x F(f)] ----------------
__global__ __launch_bounds__(256) void k_precompute_M(const float* __restrict__ Wq,
                                                      const float* __restrict__ Wk,
                                                      float* __restrict__ M) {
    int f = threadIdx.x;
    int j = blockIdx.x;
    float acc = 0.f;
    for (int d = 0; d < DD; ++d) acc += Wq[d*DD + j] * Wk[d*FF + f];
    M[j*FF + f] = acc * 0.0625f;   // scale = D^-0.5
}

// ---------------- K1: slots0 = mu + exp(ls)*noise ; qk0 = LN_s(slots0) @ M ----------------
__global__ __launch_bounds__(256) void k_init(const float* __restrict__ noise,
                                              const float* __restrict__ mu,
                                              const float* __restrict__ lsig,
                                              const float* __restrict__ gs,
                                              const float* __restrict__ bs,
                                              const float* __restrict__ M,
                                              float* __restrict__ slots,
                                              float* __restrict__ qk) {
    int b = blockIdx.x, tid = threadIdx.x;
    __shared__ float sn[SS*DD];
    __shared__ float redA[4], redB[4];
    float ps = 0.f, pq = 0.f;
    float mud = mu[tid];
    float sgd = expf(lsig[tid]);
    #pragma unroll
    for (int s = 0; s < SS; ++s) {
        int idx = s*DD + tid;
        float v = mud + sgd * noise[b*(SS*DD) + idx];
        slots[(size_t)b*(SS*DD) + idx] = v;
        sn[idx] = v;
        ps += v; pq += v*v;
    }
    #pragma unroll
    for (int m = 1; m < 64; m <<= 1) { ps += __shfl_xor(ps, m); pq += __shfl_xor(pq, m); }
    if ((tid & 63) == 0) { redA[tid>>6] = ps; redB[tid>>6] = pq; }
    __syncthreads();
    float S_ = redA[0]+redA[1]+redA[2]+redA[3];
    float Q_ = redB[0]+redB[1]+redB[2]+redB[3];
    float mean = S_ * (1.f/2048.f);
    float var  = Q_ * (1.f/2048.f) - mean*mean;
    float rinv = rsqrtf(var + 1e-5f);
    #pragma unroll
    for (int s = 0; s < SS; ++s) {
        int idx = s*DD + tid;
        sn[idx] = (sn[idx]-mean)*rinv*gs[idx] + bs[idx];
    }
    __syncthreads();
    float acc[8] = {0,0,0,0,0,0,0,0};
    for (int j = 0; j < DD; ++j) {
        float mv = M[j*FF + tid];
        #pragma unroll
        for (int s = 0; s < SS; ++s) acc[s] += sn[s*DD + j] * mv;
    }
    #pragma unroll
    for (int s = 0; s < SS; ++s) qk[((size_t)b*SS + s)*FF + tid] = acc[s];
}

// ---------------- K2: streaming attention pass over x (the 1 GB kernel) ----------------
__global__ __launch_bounds__(256) void k_attn(const float* __restrict__ x,
                                              const float* __restrict__ ln_g,
                                              const float* __restrict__ ln_b,
                                              const float* __restrict__ qk,
                                              float* __restrict__ u_part,
                                              float* __restrict__ sum_part) {
    int bid = blockIdx.x;
    int b = bid / CPB, c = bid % CPB;
    int tid = threadIdx.x, wave = tid >> 6, lane = tid & 63;
    int start = c*341 + (c < 4 ? c : 4);
    int cnt   = 341 + (c < 4 ? 1 : 0);
    const int f0 = lane * 4;

    float4 g4 = *(const float4*)&ln_g[f0];
    float4 b4 = *(const float4*)&ln_b[f0];

    float gq[8][4];
    float Gq[8], Bq[8];
    #pragma unroll
    for (int s = 0; s < SS; ++s) {
        float4 q4 = *(const float4*)&qk[((size_t)b*SS + s)*FF + f0];
        float pg = g4.x*q4.x + g4.y*q4.y + g4.z*q4.z + g4.w*q4.w;
        float pb = b4.x*q4.x + b4.y*q4.y + b4.z*q4.z + b4.w*q4.w;
        #pragma unroll
        for (int m = 1; m < 64; m <<= 1) { pg += __shfl_xor(pg, m); pb += __shfl_xor(pb, m); }
        Gq[s] = pg; Bq[s] = pb;
        gq[s][0] = g4.x*q4.x; gq[s][1] = g4.y*q4.y; gq[s][2] = g4.z*q4.z; gq[s][3] = g4.w*q4.w;
    }

    float u[8][4];
    #pragma unroll
    for (int s = 0; s < 8; ++s) { u[s][0]=0.f; u[s][1]=0.f; u[s][2]=0.f; u[s][3]=0.f; }
    float ssum[8] = {0,0,0,0,0,0,0,0};

    int myCnt = (cnt - wave + 3) >> 2;
    const float* xb = x + (size_t)b * NN * FF;
    int n = start + wave;
    float4 x4 = make_float4(0,0,0,0);
    if (myCnt > 0) x4 = *(const float4*)&xb[(size_t)n*FF + f0];

    for (int r = 0; r < myCnt; ++r) {
        int nNext = n + 4;
        float4 xnext = make_float4(0,0,0,0);
        if (r + 1 < myCnt) xnext = *(const float4*)&xb[(size_t)nNext*FF + f0];

        float vals[10];
        vals[0] = x4.x + x4.y + x4.z + x4.w;
        vals[1] = x4.x*x4.x + x4.y*x4.y + x4.z*x4.z + x4.w*x4.w;
        #pragma unroll
        for (int s = 0; s < SS; ++s)
            vals[2+s] = x4.x*gq[s][0] + x4.y*gq[s][1] + x4.z*gq[s][2] + x4.w*gq[s][3];
        #pragma unroll
        for (int i = 0; i < 10; ++i) vals[i] = waveAllSum(vals[i]);

        float mean = vals[0] * (1.f/256.f);
        float var  = vals[1] * (1.f/256.f) - mean*mean;
        float rinv = rsqrtf(var + 1e-5f);

        float lg[8];
        #pragma unroll
        for (int s = 0; s < SS; ++s) lg[s] = rinv*(vals[2+s] - mean*Gq[s]) + Bq[s];
        float mx = lg[0];
        #pragma unroll
        for (int s = 1; s < SS; ++s) mx = fmaxf(mx, lg[s]);
        float e[8]; float T = 0.f;
        #pragma unroll
        for (int s = 0; s < SS; ++s) { e[s] = __expf(lg[s] - mx); T += e[s]; }
        float inv = 1.0f / T;

        float c1 = rinv, c0 = -mean*rinv;
        float xn0 = (x4.x*c1 + c0)*g4.x + b4.x;
        float xn1 = (x4.y*c1 + c0)*g4.y + b4.y;
        float xn2 = (x4.z*c1 + c0)*g4.z + b4.z;
        float xn3 = (x4.w*c1 + c0)*g4.w + b4.w;
        #pragma unroll
        for (int s = 0; s < SS; ++s) {
            float a = e[s]*inv + EPSV;
            ssum[s] += a;
            u[s][0] += a*xn0; u[s][1] += a*xn1; u[s][2] += a*xn2; u[s][3] += a*xn3;
        }
        x4 = xnext; n = nNext;
    }

    // combine 4 waves' accumulators in LDS (barrier-phased, conflict-free contiguous stores)
    __shared__ float u_l[SS*FF];
    __shared__ float wsum[4][8];
    for (int w = 0; w < 4; ++w) {
        if (wave == w) {
            #pragma unroll
            for (int s = 0; s < SS; ++s) {
                float4* p = (float4*)&u_l[s*FF + f0];
                if (w == 0) *p = make_float4(u[s][0], u[s][1], u[s][2], u[s][3]);
                else {
                    float4 o = *p;
                    *p = make_float4(o.x+u[s][0], o.y+u[s][1], o.z+u[s][2], o.w+u[s][3]);
                }
            }
            if (lane == 0) {
                #pragma unroll
                for (int s = 0; s < SS; ++s) wsum[w][s] = ssum[s];
            }
        }
        __syncthreads();
    }
    float* up = u_part + (size_t)bid * (SS*FF);
    for (int k = tid; k < (SS*FF)/4; k += 256) ((float4*)up)[k] = ((const float4*)u_l)[k];
    if (tid < 8) sum_part[bid*8 + tid] = wsum[0][tid]+wsum[1][tid]+wsum[2][tid]+wsum[3][tid];
}

// ---------------- K3: updates -> GRU -> LN_m -> MLP (+ next-iter LN_s @ M) ----------------
template<bool LAST>
__global__ __launch_bounds__(512) void k_update(const float* __restrict__ u_part,
                                                const float* __restrict__ sum_part,
                                                float* __restrict__ slots,
                                                const float* __restrict__ Wv,
                                                const float* __restrict__ W_ih,
                                                const float* __restrict__ W_hh,
                                                const float* __restrict__ b_ih,
                                                const float* __restrict__ b_hh,
                                                const float* __restrict__ gm,
                                                const float* __restrict__ bm,
                                                const float* __restrict__ W1,
                                                const float* __restrict__ b1v,
                                                const float* __restrict__ W2,
                                                const float* __restrict__ b2v,
                                                const float* __restrict__ gs,
                                                const float* __restrict__ bs,
                                                const float* __restrict__ M,
                                                float* __restrict__ qk,
                                                float* __restrict__ outp) {
    int b = blockIdx.x, tid = threadIdx.x;
    __shared__ float u_l[2048], sl_l[2048], upd_l[2048], hn_l[2048], ml_l[2048];
    __shared__ float hid_l[SS*HH];
    __shared__ float ssums[8];
    __shared__ float redA[8], redB[8];

    { // reduce 12 partials + load slots_prev
        int k = tid;  // float4 index 0..511
        float4 acc = make_float4(0,0,0,0);
        for (int p = 0; p < CPB; ++p) {
            float4 v = ((const float4*)(u_part + ((size_t)(b*CPB + p))*2048))[k];
            acc.x += v.x; acc.y += v.y; acc.z += v.z; acc.w += v.w;
        }
        ((float4*)u_l)[k] = acc;
        ((float4*)sl_l)[k] = ((const float4*)(slots + (size_t)b*2048))[k];
    }
    if (tid < 8) {
        float s0 = 0.f;
        for (int p = 0; p < CPB; ++p) s0 += sum_part[(b*CPB + p)*8 + tid];
        ssums[tid] = s0;
    }
    __syncthreads();

    int d = tid & 255, sh = tid >> 8;   // sh in {0,1}; 4 slots each

    { // updates[s][d] = (sum_f u[s][f] Wv[d][f]) / ssum[s]
        float acc[4] = {0,0,0,0};
        for (int f = 0; f < FF; ++f) {
            float wv = Wv[d*FF + f];
            #pragma unroll
            for (int s4 = 0; s4 < 4; ++s4) acc[s4] += u_l[(sh*4+s4)*FF + f] * wv;
        }
        #pragma unroll
        for (int s4 = 0; s4 < 4; ++s4) upd_l[(sh*4+s4)*DD + d] = acc[s4] / ssums[sh*4+s4];
    }
    __syncthreads();

    float hnew[4];
    { // GRU
        float aR[4]={0,0,0,0}, aZ[4]={0,0,0,0}, aN[4]={0,0,0,0};
        float hR[4]={0,0,0,0}, hZ[4]={0,0,0,0}, hN[4]={0,0,0,0};
        for (int f = 0; f < DD; ++f) {
            float wr = W_ih[(      d)*DD + f];
            float wz = W_ih[(256 + d)*DD + f];
            float wn = W_ih[(512 + d)*DD + f];
            float vr = W_hh[(      d)*DD + f];
            float vz = W_hh[(256 + d)*DD + f];
            float vn = W_hh[(512 + d)*DD + f];
            #pragma unroll
            for (int s4 = 0; s4 < 4; ++s4) {
                float uv = upd_l[(sh*4+s4)*DD + f];
                float hv = sl_l[(sh*4+s4)*DD + f];
                aR[s4] += uv*wr; aZ[s4] += uv*wz; aN[s4] += uv*wn;
                hR[s4] += hv*vr; hZ[s4] += hv*vz; hN[s4] += hv*vn;
            }
        }
        float bir = b_ih[d], biz = b_ih[256+d], bin_ = b_ih[512+d];
        float bhr = b_hh[d], bhz = b_hh[256+d], bhn  = b_hh[512+d];
        #pragma unroll
        for (int s4 = 0; s4 < 4; ++s4) {
            float r  = 1.f/(1.f + __expf(-(aR[s4]+bir + hR[s4]+bhr)));
            float z  = 1.f/(1.f + __expf(-(aZ[s4]+biz + hZ[s4]+bhz)));
            float nn = tanhf(aN[s4]+bin_ + r*(hN[s4]+bhn));
            float hp = sl_l[(sh*4+s4)*DD + d];
            hnew[s4] = (1.f - z)*nn + z*hp;
            hn_l[(sh*4+s4)*DD + d] = hnew[s4];
        }
    }
    __syncthreads();

    float mean, rinv;
    { // LN_m stats over all 2048
        float ps = 0.f, pq = 0.f;
        #pragma unroll
        for (int s4 = 0; s4 < 4; ++s4) { ps += hnew[s4]; pq += hnew[s4]*hnew[s4]; }
        #pragma unroll
        for (int m = 1; m < 64; m <<= 1) { ps += __shfl_xor(ps, m); pq += __shfl_xor(pq, m); }
        if ((tid & 63) == 0) { redA[tid>>6] = ps; redB[tid>>6] = pq; }
        __syncthreads();
        float S_ = 0.f, Q_ = 0.f;
        #pragma unroll
        for (int w = 0; w < 8; ++w) { S_ += redA[w]; Q_ += redB[w]; }
        mean = S_ * (1.f/2048.f);
        float var = Q_ * (1.f/2048.f) - mean*mean;
        rinv = rsqrtf(var + 1e-5f);
        __syncthreads();
    }
    { // ml = LN_m(hnew)*gm + bm
        int k4 = tid*4;
        float4 h4 = *(const float4*)&hn_l[k4];
        float4 g4 = *(const float4*)&gm[k4];
        float4 bb = *(const float4*)&bm[k4];
        ml_l[k4+0] = (h4.x-mean)*rinv*g4.x + bb.x;
        ml_l[k4+1] = (h4.y-mean)*rinv*g4.y + bb.y;
        ml_l[k4+2] = (h4.z-mean)*rinv*g4.z + bb.z;
        ml_l[k4+3] = (h4.w-mean)*rinv*g4.w + bb.w;
    }
    __syncthreads();

    { // MLP layer 1: hid[s][h] = relu(ml[s] . W1[h] + b1)
        int h = tid;
        float acc[8] = {0,0,0,0,0,0,0,0};
        for (int dd2 = 0; dd2 < DD; ++dd2) {
            float w1 = W1[h*DD + dd2];
            #pragma unroll
            for (int s = 0; s < SS; ++s) acc[s] += ml_l[s*DD + dd2] * w1;
        }
        float bb1 = b1v[h];
        #pragma unroll
        for (int s = 0; s < SS; ++s) hid_l[s*HH + h] = fmaxf(acc[s] + bb1, 0.f);
    }
    __syncthreads();

    float outv[4];
    { // MLP layer 2 + residual
        float acc[4] = {0,0,0,0};
        for (int h = 0; h < HH; ++h) {
            float w2 = W2[d*HH + h];
            #pragma unroll
            for (int s4 = 0; s4 < 4; ++s4) acc[s4] += hid_l[(sh*4+s4)*HH + h] * w2;
        }
        float bb2 = b2v[d];
        #pragma unroll
        for (int s4 = 0; s4 < 4; ++s4) outv[s4] = hn_l[(sh*4+s4)*DD + d] + acc[s4] + bb2;
    }

    if (LAST) {
        #pragma unroll
        for (int s4 = 0; s4 < 4; ++s4)
            outp[((size_t)b*SS + sh*4+s4)*DD + d] = outv[s4];
        return;
    }

    #pragma unroll
    for (int s4 = 0; s4 < 4; ++s4) {
        slots[(size_t)b*2048 + (sh*4+s4)*DD + d] = outv[s4];
        upd_l[(sh*4+s4)*DD + d] = outv[s4];   // stage for LN_s
    }
    float mean2, rinv2;
    { // LN_s stats of new slots
        float ps = 0.f, pq = 0.f;
        #pragma unroll
        for (int s4 = 0; s4 < 4; ++s4) { ps += outv[s4]; pq += outv[s4]*outv[s4]; }
        #pragma unroll
        for (int m = 1; m < 64; m <<= 1) { ps += __shfl_xor(ps, m); pq += __shfl_xor(pq, m); }
        __syncthreads();   // protect redA/redB reuse AND make upd_l visible
        if ((tid & 63) == 0) { redA[tid>>6] = ps; redB[tid>>6] = pq; }
        __syncthreads();
        float S_ = 0.f, Q_ = 0.f;
        #pragma unroll
        for (int w = 0; w < 8; ++w) { S_ += redA[w]; Q_ += redB[w]; }
        mean2 = S_ * (1.f/2048.f);
        float var = Q_ * (1.f/2048.f) - mean2*mean2;
        rinv2 = rsqrtf(var + 1e-5f);
    }
    { // sn (reuse u_l)
        int k4 = tid*4;
        #pragma unroll
        for (int i = 0; i < 4; ++i) {
            int idx = k4 + i;
            u_l[idx] = (upd_l[idx]-mean2)*rinv2*gs[idx] + bs[idx];
        }
    }
    __syncthreads();
    { // qk_next = sn @ M
        float acc[4] = {0,0,0,0};
        for (int j = 0; j < DD; ++j) {
            float mv = M[j*FF + d];
            #pragma unroll
            for (int s4 = 0; s4 < 4; ++s4) acc[s4] += u_l[(sh*4+s4)*DD + j] * mv;
        }
        #pragma unroll
        for (int s4 = 0; s4 < 4; ++s4)
            qk[((size_t)b*SS + sh*4+s4)*FF + d] = acc[s4];
    }
}

// ---------------- launch ----------------
extern "C" void kernel_launch(void* const* d_in, const int* in_sizes, int n_in,
                              void* d_out, int out_size, void* d_ws, size_t ws_size,
                              hipStream_t stream) {
    const float* x        = (const float*)d_in[0];
    const float* noise    = (const float*)d_in[1];
    const float* ln_in_g  = (const float*)d_in[2];
    const float* ln_in_b  = (const float*)d_in[3];
    const float* ln_s_g   = (const float*)d_in[4];
    const float* ln_s_b   = (const float*)d_in[5];
    const float* ln_m_g   = (const float*)d_in[6];
    const float* ln_m_b   = (const float*)d_in[7];
    const float* slots_mu = (const float*)d_in[8];
    const float* slots_ls = (const float*)d_in[9];
    const float* Wq       = (const float*)d_in[10];
    const float* Wk       = (const float*)d_in[11];
    const float* Wv       = (const float*)d_in[12];
    const float* W_ih     = (const float*)d_in[13];
    const float* W_hh     = (const float*)d_in[14];
    const float* b_ih     = (const float*)d_in[15];
    const float* b_hh     = (const float*)d_in[16];
    const float* W1       = (const float*)d_in[17];
    const float* b1       = (const float*)d_in[18];
    const float* W2       = (const float*)d_in[19];
    const float* b2       = (const float*)d_in[20];

    float* ws       = (float*)d_ws;
    float* M        = ws;                          // 65536
    float* qk       = ws + 65536;                  // B*S*F = 131072
    float* slots    = ws + 65536 + 131072;         // B*S*D = 131072
    float* u_part   = ws + 327680;                 // NBLK*2048 = 1572864
    float* sum_part = ws + 327680 + NBLK*2048;     // NBLK*8
    float* outp     = (float*)d_out;

    k_precompute_M<<<256, 256, 0, stream>>>(Wq, Wk, M);
    k_init<<<BB, 256, 0, stream>>>(noise, slots_mu, slots_ls, ln_s_g, ln_s_b, M, slots, qk);
    for (int it = 0; it < 3; ++it) {
        k_attn<<<NBLK, 256, 0, stream>>>(x, ln_in_g, ln_in_b, qk, u_part, sum_part);
        if (it < 2) {
            k_update<false><<<BB, 512, 0, stream>>>(u_part, sum_part, slots, Wv, W_ih, W_hh,
                b_ih, b_hh, ln_m_g, ln_m_b, W1, b1, W2, b2, ln_s_g, ln_s_b, M, qk, outp);
        } else {
            k_update<true><<<BB, 512, 0, stream>>>(u_part, sum_part, slots, Wv, W_ih, W_hh,
                b_ih, b_hh, ln_m_g, ln_m_b, W1, b1, W2, b2, ln_s_g, ln_s_b, M, qk, outp);
        }
    }
}

// Round 2
// 1128.938 us; speedup vs baseline: 1.3635x; 1.3635x over previous
//
#include <hip/hip_runtime.h>
#include <hip/hip_bf16.h>
#include <math.h>

#define BB 64
#define NN 4096
#define FF 256
#define DD 256
#define SS 8
#define HH 512
#define CPB 12                 // attention blocks per batch -> grid 768 = 3 blocks/CU
#define NBLK (BB*CPB)
#define EPSV 1e-8f

// ---------------- wave reduction helpers ----------------
template<int CTRL>
__device__ __forceinline__ float dppAdd(float v) {
    int moved = __builtin_amdgcn_update_dpp(0, __float_as_int(v), CTRL, 0xF, 0xF, true);
    return v + __int_as_float(moved);
}
// full 64-lane all-reduce sum: DPP for xor1/2/4/8 (VALU pipe), shfl for 16/32
__device__ __forceinline__ float waveAllSum(float v) {
    v = dppAdd<0xB1>(v);    // quad_perm [1,0,3,2]  == xor 1
    v = dppAdd<0x4E>(v);    // quad_perm [2,3,0,1]  == xor 2
    v = dppAdd<0x141>(v);   // row_half_mirror
    v = dppAdd<0x140>(v);   // row_mirror
    v += __shfl_xor(v, 16);
    v += __shfl_xor(v, 32);
    return v;
}

// ---------------- K0: M = scale * Wq^T @ Wk  [D(j) x F(f)] ----------------
__global__ __launch_bounds__(256) void k_precompute_M(const float* __restrict__ Wq,
                                                      const float* __restrict__ Wk,
                                                      float* __restrict__ M) {
    int f = threadIdx.x;
    int j = blockIdx.x;
    float acc = 0.f;
    for (int d = 0; d < DD; ++d) acc += Wq[d*DD + j] * Wk[d*FF + f];
    M[j*FF + f] = acc * 0.0625f;   // scale = D^-0.5
}

// ---------------- K0b: tiled transpose dst[C][R] = src[R][C]^T ----------------
__global__ __launch_bounds__(256) void k_transpose(const float* __restrict__ src,
                                                   float* __restrict__ dst,
                                                   int R, int C) {
    __shared__ float t[32][33];
    int c0 = blockIdx.x * 32, r0 = blockIdx.y * 32;
    int tx = threadIdx.x & 31, ty = threadIdx.x >> 5;   // ty in [0,8)
    #pragma unroll
    for (int i = 0; i < 32; i += 8)
        t[ty + i][tx] = src[(size_t)(r0 + ty + i) * C + c0 + tx];
    __syncthreads();
    #pragma unroll
    for (int i = 0; i < 32; i += 8)
        dst[(size_t)(c0 + ty + i) * R + r0 + tx] = t[tx][ty + i];
}

// ---------------- K1: slots0 = mu + exp(ls)*noise ; qk0 = LN_s(slots0) @ M ----------------
__global__ __launch_bounds__(256) void k_init(const float* __restrict__ noise,
                                              const float* __restrict__ mu,
                                              const float* __restrict__ lsig,
                                              const float* __restrict__ gs,
                                              const float* __restrict__ bs,
                                              const float* __restrict__ M,
                                              float* __restrict__ slots,
                                              float* __restrict__ qk) {
    int b = blockIdx.x, tid = threadIdx.x;
    __shared__ float sn[SS*DD];
    __shared__ float redA[4], redB[4];
    float ps = 0.f, pq = 0.f;
    float mud = mu[tid];
    float sgd = expf(lsig[tid]);
    #pragma unroll
    for (int s = 0; s < SS; ++s) {
        int idx = s*DD + tid;
        float v = mud + sgd * noise[b*(SS*DD) + idx];
        slots[(size_t)b*(SS*DD) + idx] = v;
        sn[idx] = v;
        ps += v; pq += v*v;
    }
    #pragma unroll
    for (int m = 1; m < 64; m <<= 1) { ps += __shfl_xor(ps, m); pq += __shfl_xor(pq, m); }
    if ((tid & 63) == 0) { redA[tid>>6] = ps; redB[tid>>6] = pq; }
    __syncthreads();
    float S_ = redA[0]+redA[1]+redA[2]+redA[3];
    float Q_ = redB[0]+redB[1]+redB[2]+redB[3];
    float mean = S_ * (1.f/2048.f);
    float var  = Q_ * (1.f/2048.f) - mean*mean;
    float rinv = rsqrtf(var + 1e-5f);
    #pragma unroll
    for (int s = 0; s < SS; ++s) {
        int idx = s*DD + tid;
        sn[idx] = (sn[idx]-mean)*rinv*gs[idx] + bs[idx];
    }
    __syncthreads();
    float acc[8] = {0,0,0,0,0,0,0,0};
    for (int j = 0; j < DD; ++j) {
        float mv = M[j*FF + tid];
        #pragma unroll
        for (int s = 0; s < SS; ++s) acc[s] += sn[s*DD + j] * mv;
    }
    #pragma unroll
    for (int s = 0; s < SS; ++s) qk[((size_t)b*SS + s)*FF + tid] = acc[s];
}

// ---------------- K2: streaming attention pass over x ----------------
__global__ __launch_bounds__(256, 3) void k_attn(const float* __restrict__ x,
                                                 const float* __restrict__ ln_g,
                                                 const float* __restrict__ ln_b,
                                                 const float* __restrict__ qk,
                                                 float* __restrict__ u_part,
                                                 float* __restrict__ sum_part) {
    int bid = blockIdx.x;
    int b = bid / CPB, c = bid % CPB;
    int tid = threadIdx.x, wave = tid >> 6, lane = tid & 63;
    int start = c*341 + (c < 4 ? c : 4);
    int cnt   = 341 + (c < 4 ? 1 : 0);
    int end   = start + cnt;
    const int f0 = lane * 4;

    float4 g4 = *(const float4*)&ln_g[f0];

    float gq[8][4];
    float Gq[8], Bq[8];
    {
        float4 b4 = *(const float4*)&ln_b[f0];
        #pragma unroll
        for (int s = 0; s < SS; ++s) {
            float4 q4 = *(const float4*)&qk[((size_t)b*SS + s)*FF + f0];
            gq[s][0] = g4.x*q4.x; gq[s][1] = g4.y*q4.y; gq[s][2] = g4.z*q4.z; gq[s][3] = g4.w*q4.w;
            float pg = gq[s][0] + gq[s][1] + gq[s][2] + gq[s][3];
            float pb = b4.x*q4.x + b4.y*q4.y + b4.z*q4.z + b4.w*q4.w;
            Gq[s] = waveAllSum(pg);
            Bq[s] = waveAllSum(pb);
        }
    }

    float u[8][4];
    #pragma unroll
    for (int s = 0; s < 8; ++s) { u[s][0]=0.f; u[s][1]=0.f; u[s][2]=0.f; u[s][3]=0.f; }
    float ssum[8] = {0,0,0,0,0,0,0,0};

    const float* xb = x + (size_t)b * NN * FF;
    // wave handles row pairs {start+2w+8p, start+2w+8p+1}
    int row = start + wave*2;
    int iters = (cnt - wave*2 + 7) >> 3;
    float4 xA = make_float4(0,0,0,0), xB = make_float4(0,0,0,0);
    float vA = 0.f, vB = 0.f;
    if (row < end)     { xA = *(const float4*)&xb[(size_t)row*FF + f0];     vA = 1.f; }
    if (row + 1 < end) { xB = *(const float4*)&xb[(size_t)(row+1)*FF + f0]; vB = 1.f; }

    for (int r = 0; r < iters; ++r) {
        int rowN = row + 8;
        float4 nA = make_float4(0,0,0,0), nB = make_float4(0,0,0,0);
        float nvA = 0.f, nvB = 0.f;
        if (r + 1 < iters) {
            if (rowN < end)     { nA = *(const float4*)&xb[(size_t)rowN*FF + f0];     nvA = 1.f; }
            if (rowN + 1 < end) { nB = *(const float4*)&xb[(size_t)(rowN+1)*FF + f0]; nvB = 1.f; }
        }

        float vals[20];
        vals[0]  = xA.x + xA.y + xA.z + xA.w;
        vals[1]  = xA.x*xA.x + xA.y*xA.y + xA.z*xA.z + xA.w*xA.w;
        vals[10] = xB.x + xB.y + xB.z + xB.w;
        vals[11] = xB.x*xB.x + xB.y*xB.y + xB.z*xB.z + xB.w*xB.w;
        #pragma unroll
        for (int s = 0; s < SS; ++s) {
            vals[2+s]  = xA.x*gq[s][0] + xA.y*gq[s][1] + xA.z*gq[s][2] + xA.w*gq[s][3];
            vals[12+s] = xB.x*gq[s][0] + xB.y*gq[s][1] + xB.z*gq[s][2] + xB.w*gq[s][3];
        }
        #pragma unroll
        for (int i = 0; i < 20; ++i) vals[i] = waveAllSum(vals[i]);

        // process the two rows (independent chains)
        #pragma unroll
        for (int half = 0; half < 2; ++half) {
            float sA  = half ? vals[10] : vals[0];
            float sQ  = half ? vals[11] : vals[1];
            const float* dv = half ? &vals[12] : &vals[2];
            float4 xr = half ? xB : xA;
            float valid = half ? vB : vA;

            float mean = sA * (1.f/256.f);
            float var  = sQ * (1.f/256.f) - mean*mean;
            float rinv = rsqrtf(var + 1e-5f);
            float mr   = mean * rinv;
            float lg[8];
            #pragma unroll
            for (int s = 0; s < SS; ++s) lg[s] = rinv*dv[s] - mr*Gq[s] + Bq[s];
            float mx = fmaxf(fmaxf(fmaxf(lg[0],lg[1]), fmaxf(lg[2],lg[3])),
                             fmaxf(fmaxf(lg[4],lg[5]), fmaxf(lg[6],lg[7])));
            float e[8]; float T = 0.f;
            #pragma unroll
            for (int s = 0; s < SS; ++s) { e[s] = __expf(lg[s]-mx); T += e[s]; }
            float inv = valid / T;
            float t0 = xr.x*rinv - mr, t1 = xr.y*rinv - mr;
            float t2 = xr.z*rinv - mr, t3 = xr.w*rinv - mr;
            #pragma unroll
            for (int s = 0; s < SS; ++s) {
                float a = e[s]*inv + EPSV*valid;
                ssum[s] += a;
                u[s][0] += a*t0; u[s][1] += a*t1; u[s][2] += a*t2; u[s][3] += a*t3;
            }
        }
        row = rowN; xA = nA; xB = nB; vA = nvA; vB = nvB;
    }

    // combine 4 waves; fold gamma here, beta-term via ssum at the end
    __shared__ float u_l[SS*FF];
    __shared__ float wsum[4][8];
    __shared__ float stot[8];
    for (int w = 0; w < 4; ++w) {
        if (wave == w) {
            #pragma unroll
            for (int s = 0; s < SS; ++s) {
                float4* p = (float4*)&u_l[s*FF + f0];
                float4 add = make_float4(u[s][0]*g4.x, u[s][1]*g4.y, u[s][2]*g4.z, u[s][3]*g4.w);
                if (w == 0) *p = add;
                else { float4 o = *p; *p = make_float4(o.x+add.x, o.y+add.y, o.z+add.z, o.w+add.w); }
            }
            if (lane == 0) {
                #pragma unroll
                for (int s = 0; s < SS; ++s) wsum[w][s] = ssum[s];
            }
        }
        __syncthreads();
    }
    if (tid < 8) stot[tid] = wsum[0][tid]+wsum[1][tid]+wsum[2][tid]+wsum[3][tid];
    __syncthreads();
    float* up = u_part + (size_t)bid * (SS*FF);
    for (int k = tid; k < (SS*FF)/4; k += 256) {
        int s = k >> 6; int f = (k & 63) << 2;
        float4 uv = ((const float4*)u_l)[k];
        float4 bb = *(const float4*)&ln_b[f];
        float st = stot[s];
        uv.x += bb.x*st; uv.y += bb.y*st; uv.z += bb.z*st; uv.w += bb.w*st;
        ((float4*)up)[k] = uv;
    }
    if (tid < 8) sum_part[bid*8 + tid] = stot[tid];
}

// ---------------- K3: updates -> GRU -> LN_m -> MLP (+ next-iter LN_s @ M) ----------------
template<bool LAST>
__global__ __launch_bounds__(1024, 4) void k_update(const float* __restrict__ u_part,
                                                    const float* __restrict__ sum_part,
                                                    float* __restrict__ slots,
                                                    const float* __restrict__ WvT,
                                                    const float* __restrict__ WihT,
                                                    const float* __restrict__ WhhT,
                                                    const float* __restrict__ b_ih,
                                                    const float* __restrict__ b_hh,
                                                    const float* __restrict__ gm,
                                                    const float* __restrict__ bm,
                                                    const float* __restrict__ W1T,
                                                    const float* __restrict__ b1v,
                                                    const float* __restrict__ W2T,
                                                    const float* __restrict__ b2v,
                                                    const float* __restrict__ gs,
                                                    const float* __restrict__ bs,
                                                    const float* __restrict__ M,
                                                    float* __restrict__ qk,
                                                    float* __restrict__ outp) {
    int b = blockIdx.x, tid = threadIdx.x;
    __shared__ float u_l[2048], sl_l[2048], upd_l[2048], hn_l[2048], ml_l[2048];
    __shared__ float hid_l[SS*HH];
    __shared__ float ssinv[8];
    __shared__ float redA[16], redB[16];

    if (tid < 512) {  // reduce CPB partials (coalesced float4) + load slots_prev
        float4 acc = make_float4(0,0,0,0);
        const float4* upp = (const float4*)(u_part + (size_t)b*CPB*2048);
        #pragma unroll 4
        for (int p = 0; p < CPB; ++p) {
            float4 v = upp[p*512 + tid];
            acc.x += v.x; acc.y += v.y; acc.z += v.z; acc.w += v.w;
        }
        ((float4*)u_l)[tid] = acc;
        ((float4*)sl_l)[tid] = ((const float4*)(slots + (size_t)b*2048))[tid];
    } else if (tid < 520) {
        int s = tid - 512;
        float s0_ = 0.f;
        for (int p = 0; p < CPB; ++p) s0_ += sum_part[(b*CPB + p)*8 + s];
        ssinv[s] = 1.0f / s0_;
    }
    __syncthreads();

    int d = tid & 255, sh = tid >> 8;      // sh in [0,4): 2 slots per thread
    int s0 = sh*2, s1 = sh*2+1;

    { // updates[s][d] = (sum_f u[s][f] WvT[f][d]) * ssinv[s]
        float a0 = 0.f, a1 = 0.f;
        const float4* uv = (const float4*)u_l;
        for (int f4 = 0; f4 < 64; ++f4) {
            float4 c0 = uv[s0*64 + f4];
            float4 c1 = uv[s1*64 + f4];
            const float* wb = WvT + (f4*4)*DD + d;
            float w0 = wb[0], w1 = wb[DD], w2 = wb[2*DD], w3 = wb[3*DD];
            a0 += c0.x*w0 + c0.y*w1 + c0.z*w2 + c0.w*w3;
            a1 += c1.x*w0 + c1.y*w1 + c1.z*w2 + c1.w*w3;
        }
        upd_l[s0*DD + d] = a0 * ssinv[s0];
        upd_l[s1*DD + d] = a1 * ssinv[s1];
    }
    __syncthreads();

    float hnew0, hnew1;
    { // GRU
        float aR0=0.f,aZ0=0.f,aN0=0.f,hR0=0.f,hZ0=0.f,hN0=0.f;
        float aR1=0.f,aZ1=0.f,aN1=0.f,hR1=0.f,hZ1=0.f,hN1=0.f;
        const float4* updv = (const float4*)upd_l;
        const float4* slv  = (const float4*)sl_l;
        for (int f4 = 0; f4 < 64; ++f4) {
            float4 u0 = updv[s0*64 + f4];
            float4 u1 = updv[s1*64 + f4];
            float4 p0 = slv[s0*64 + f4];
            float4 p1 = slv[s1*64 + f4];
            const float* wb = WihT + (size_t)(f4*4)*768 + d;
            const float* vb = WhhT + (size_t)(f4*4)*768 + d;
#define GSTEP(J, U0c, U1c, P0c, P1c) { \
            float wr = wb[J*768], wz = wb[J*768+256], wn = wb[J*768+512]; \
            float vr = vb[J*768], vz = vb[J*768+256], vn = vb[J*768+512]; \
            aR0 += U0c*wr; aZ0 += U0c*wz; aN0 += U0c*wn; \
            aR1 += U1c*wr; aZ1 += U1c*wz; aN1 += U1c*wn; \
            hR0 += P0c*vr; hZ0 += P0c*vz; hN0 += P0c*vn; \
            hR1 += P1c*vr; hZ1 += P1c*vz; hN1 += P1c*vn; }
            GSTEP(0, u0.x, u1.x, p0.x, p1.x)
            GSTEP(1, u0.y, u1.y, p0.y, p1.y)
            GSTEP(2, u0.z, u1.z, p0.z, p1.z)
            GSTEP(3, u0.w, u1.w, p0.w, p1.w)
#undef GSTEP
        }
        float bir = b_ih[d], biz = b_ih[256+d], bin_ = b_ih[512+d];
        float bhr = b_hh[d], bhz = b_hh[256+d], bhn  = b_hh[512+d];
        {
            float r  = 1.f/(1.f + __expf(-(aR0+bir + hR0+bhr)));
            float z  = 1.f/(1.f + __expf(-(aZ0+biz + hZ0+bhz)));
            float nn = tanhf(aN0+bin_ + r*(hN0+bhn));
            float hp = sl_l[s0*DD + d];
            hnew0 = (1.f - z)*nn + z*hp;
            hn_l[s0*DD + d] = hnew0;
        }
        {
            float r  = 1.f/(1.f + __expf(-(aR1+bir + hR1+bhr)));
            float z  = 1.f/(1.f + __expf(-(aZ1+biz + hZ1+bhz)));
            float nn = tanhf(aN1+bin_ + r*(hN1+bhn));
            float hp = sl_l[s1*DD + d];
            hnew1 = (1.f - z)*nn + z*hp;
            hn_l[s1*DD + d] = hnew1;
        }
    }
    __syncthreads();

    float mean, rinv;
    { // LN_m stats over 2048
        float ps = hnew0 + hnew1, pq = hnew0*hnew0 + hnew1*hnew1;
        #pragma unroll
        for (int m = 1; m < 64; m <<= 1) { ps += __shfl_xor(ps, m); pq += __shfl_xor(pq, m); }
        if ((tid & 63) == 0) { redA[tid>>6] = ps; redB[tid>>6] = pq; }
        __syncthreads();
        float S_ = 0.f, Q_ = 0.f;
        #pragma unroll
        for (int w = 0; w < 16; ++w) { S_ += redA[w]; Q_ += redB[w]; }
        mean = S_ * (1.f/2048.f);
        float var = Q_ * (1.f/2048.f) - mean*mean;
        rinv = rsqrtf(var + 1e-5f);
        __syncthreads();
    }
    { // ml = LN_m(hnew)*gm + bm  (2 elems/thread)
        int k2 = tid*2;
        float2 h2 = *(const float2*)&hn_l[k2];
        float2 gg = *(const float2*)&gm[k2];
        float2 bb = *(const float2*)&bm[k2];
        ml_l[k2]   = (h2.x-mean)*rinv*gg.x + bb.x;
        ml_l[k2+1] = (h2.y-mean)*rinv*gg.y + bb.y;
    }
    __syncthreads();

    { // MLP1: hid[s][h] = relu(ml[s] . W1T[:,h] + b1)
        int h = tid & 511, hg = tid >> 9;   // hg in {0,1}: slots hg*4..hg*4+3
        float acc0=0.f, acc1=0.f, acc2=0.f, acc3=0.f;
        const float4* mlv = (const float4*)ml_l;
        for (int d4 = 0; d4 < 64; ++d4) {
            float4 m0 = mlv[(hg*4+0)*64 + d4];
            float4 m1 = mlv[(hg*4+1)*64 + d4];
            float4 m2 = mlv[(hg*4+2)*64 + d4];
            float4 m3 = mlv[(hg*4+3)*64 + d4];
            const float* wb = W1T + (size_t)(d4*4)*HH + h;
#define MSTEP(J, C0, C1, C2, C3) { \
            float w1 = wb[J*HH]; \
            acc0 += C0*w1; acc1 += C1*w1; acc2 += C2*w1; acc3 += C3*w1; }
            MSTEP(0, m0.x, m1.x, m2.x, m3.x)
            MSTEP(1, m0.y, m1.y, m2.y, m3.y)
            MSTEP(2, m0.z, m1.z, m2.z, m3.z)
            MSTEP(3, m0.w, m1.w, m2.w, m3.w)
#undef MSTEP
        }
        float bb1 = b1v[h];
        hid_l[(hg*4+0)*HH + h] = fmaxf(acc0 + bb1, 0.f);
        hid_l[(hg*4+1)*HH + h] = fmaxf(acc1 + bb1, 0.f);
        hid_l[(hg*4+2)*HH + h] = fmaxf(acc2 + bb1, 0.f);
        hid_l[(hg*4+3)*HH + h] = fmaxf(acc3 + bb1, 0.f);
    }
    __syncthreads();

    float out0, out1;
    { // MLP2 + residual
        float a0 = 0.f, a1 = 0.f;
        const float4* hv = (const float4*)hid_l;
        for (int h4 = 0; h4 < 128; ++h4) {
            float4 q0 = hv[s0*128 + h4];
            float4 q1 = hv[s1*128 + h4];
            const float* wb = W2T + (size_t)(h4*4)*DD + d;
            float w0 = wb[0], w1 = wb[DD], w2 = wb[2*DD], w3 = wb[3*DD];
            a0 += q0.x*w0 + q0.y*w1 + q0.z*w2 + q0.w*w3;
            a1 += q1.x*w0 + q1.y*w1 + q1.z*w2 + q1.w*w3;
        }
        float bb2 = b2v[d];
        out0 = hn_l[s0*DD + d] + a0 + bb2;
        out1 = hn_l[s1*DD + d] + a1 + bb2;
    }

    if (LAST) {
        outp[((size_t)b*SS + s0)*DD + d] = out0;
        outp[((size_t)b*SS + s1)*DD + d] = out1;
        return;
    }

    slots[(size_t)b*2048 + s0*DD + d] = out0;
    slots[(size_t)b*2048 + s1*DD + d] = out1;
    upd_l[s0*DD + d] = out0;           // stage new slots for LN_s
    upd_l[s1*DD + d] = out1;
    float mean2, rinv2;
    { // LN_s stats of new slots
        float ps = out0 + out1, pq = out0*out0 + out1*out1;
        #pragma unroll
        for (int m = 1; m < 64; m <<= 1) { ps += __shfl_xor(ps, m); pq += __shfl_xor(pq, m); }
        if ((tid & 63) == 0) { redA[tid>>6] = ps; redB[tid>>6] = pq; }
        __syncthreads();
        float S_ = 0.f, Q_ = 0.f;
        #pragma unroll
        for (int w = 0; w < 16; ++w) { S_ += redA[w]; Q_ += redB[w]; }
        mean2 = S_ * (1.f/2048.f);
        float var = Q_ * (1.f/2048.f) - mean2*mean2;
        rinv2 = rsqrtf(var + 1e-5f);
    }
    { // sn into ml_l (free now)
        int k2 = tid*2;
        float2 sv = *(const float2*)&upd_l[k2];
        float2 gg = *(const float2*)&gs[k2];
        float2 bb = *(const float2*)&bs[k2];
        ml_l[k2]   = (sv.x-mean2)*rinv2*gg.x + bb.x;
        ml_l[k2+1] = (sv.y-mean2)*rinv2*gg.y + bb.y;
    }
    __syncthreads();
    { // qk_next = sn @ M
        float a0 = 0.f, a1 = 0.f;
        const float4* sv = (const float4*)ml_l;
        for (int j4 = 0; j4 < 64; ++j4) {
            float4 c0 = sv[s0*64 + j4];
            float4 c1 = sv[s1*64 + j4];
            const float* mb = M + (size_t)(j4*4)*FF + d;
            float w0 = mb[0], w1 = mb[FF], w2 = mb[2*FF], w3 = mb[3*FF];
            a0 += c0.x*w0 + c0.y*w1 + c0.z*w2 + c0.w*w3;
            a1 += c1.x*w0 + c1.y*w1 + c1.z*w2 + c1.w*w3;
        }
        qk[((size_t)b*SS + s0)*FF + d] = a0;
        qk[((size_t)b*SS + s1)*FF + d] = a1;
    }
}

// ---------------- launch ----------------
extern "C" void kernel_launch(void* const* d_in, const int* in_sizes, int n_in,
                              void* d_out, int out_size, void* d_ws, size_t ws_size,
                              hipStream_t stream) {
    const float* x        = (const float*)d_in[0];
    const float* noise    = (const float*)d_in[1];
    const float* ln_in_g  = (const float*)d_in[2];
    const float* ln_in_b  = (const float*)d_in[3];
    const float* ln_s_g   = (const float*)d_in[4];
    const float* ln_s_b   = (const float*)d_in[5];
    const float* ln_m_g   = (const float*)d_in[6];
    const float* ln_m_b   = (const float*)d_in[7];
    const float* slots_mu = (const float*)d_in[8];
    const float* slots_ls = (const float*)d_in[9];
    const float* Wq       = (const float*)d_in[10];
    const float* Wk       = (const float*)d_in[11];
    const float* Wv       = (const float*)d_in[12];
    const float* W_ih     = (const float*)d_in[13];
    const float* W_hh     = (const float*)d_in[14];
    const float* b_ih     = (const float*)d_in[15];
    const float* b_hh     = (const float*)d_in[16];
    const float* W1       = (const float*)d_in[17];
    const float* b1       = (const float*)d_in[18];
    const float* W2       = (const float*)d_in[19];
    const float* b2       = (const float*)d_in[20];

    float* ws       = (float*)d_ws;
    float* M        = ws;                      // 65536
    float* qk       = M + 65536;               // 131072
    float* slots    = qk + 131072;             // 131072
    float* WvT      = slots + 131072;          // 65536
    float* WihT     = WvT + 65536;             // 196608
    float* WhhT     = WihT + 196608;           // 196608
    float* W1T      = WhhT + 196608;           // 131072
    float* W2T      = W1T + 131072;            // 131072
    float* u_part   = W2T + 131072;            // NBLK*2048 = 1572864
    float* sum_part = u_part + (size_t)NBLK*2048;  // 6144
    float* outp     = (float*)d_out;

    k_precompute_M<<<256, 256, 0, stream>>>(Wq, Wk, M);
    k_transpose<<<dim3(256/32, 256/32), 256, 0, stream>>>(Wv,   WvT,  256, 256);
    k_transpose<<<dim3(256/32, 768/32), 256, 0, stream>>>(W_ih, WihT, 768, 256);
    k_transpose<<<dim3(256/32, 768/32), 256, 0, stream>>>(W_hh, WhhT, 768, 256);
    k_transpose<<<dim3(256/32, 512/32), 256, 0, stream>>>(W1,   W1T,  512, 256);
    k_transpose<<<dim3(512/32, 256/32), 256, 0, stream>>>(W2,   W2T,  256, 512);
    k_init<<<BB, 256, 0, stream>>>(noise, slots_mu, slots_ls, ln_s_g, ln_s_b, M, slots, qk);
    for (int it = 0; it < 3; ++it) {
        k_attn<<<NBLK, 256, 0, stream>>>(x, ln_in_g, ln_in_b, qk, u_part, sum_part);
        if (it < 2) {
            k_update<false><<<BB, 1024, 0, stream>>>(u_part, sum_part, slots, WvT, WihT, WhhT,
                b_ih, b_hh, ln_m_g, ln_m_b, W1T, b1, W2T, b2, ln_s_g, ln_s_b, M, qk, outp);
        } else {
            k_update<true><<<BB, 1024, 0, stream>>>(u_part, sum_part, slots, WvT, WihT, WhhT,
                b_ih, b_hh, ln_m_g, ln_m_b, W1T, b1, W2T, b2, ln_s_g, ln_s_b, M, qk, outp);
        }
    }
}

// Round 3
// 1022.983 us; speedup vs baseline: 1.5047x; 1.1036x over previous
//
#include <hip/hip_runtime.h>
#include <hip/hip_bf16.h>
#include <math.h>

#define BB 64
#define NN 4096
#define FF 256
#define DD 256
#define SS 8
#define HH 512
#define CPB 16                 // attention blocks per batch -> grid 1024, 256 rows/block, 64/wave
#define NBLK (BB*CPB)
#define EPSV 1e-8f

// ---------------- wave reduction helpers ----------------
template<int CTRL>
__device__ __forceinline__ float dppAdd(float v) {
    int moved = __builtin_amdgcn_update_dpp(0, __float_as_int(v), CTRL, 0xF, 0xF, true);
    return v + __int_as_float(moved);
}
__device__ __forceinline__ float waveAllSum(float v) {
    v = dppAdd<0xB1>(v);    // xor 1
    v = dppAdd<0x4E>(v);    // xor 2
    v = dppAdd<0x141>(v);   // half-mirror (4-group)
    v = dppAdd<0x140>(v);   // mirror (8-group)
    v += __shfl_xor(v, 16);
    v += __shfl_xor(v, 32);
    return v;
}

// ---------------- K0: M = scale * Wq^T @ Wk  [D(j) x F(f)] ----------------
__global__ __launch_bounds__(256) void k_precompute_M(const float* __restrict__ Wq,
                                                      const float* __restrict__ Wk,
                                                      float* __restrict__ M) {
    int f = threadIdx.x;
    int j = blockIdx.x;
    float acc = 0.f;
    for (int d = 0; d < DD; ++d) acc += Wq[d*DD + j] * Wk[d*FF + f];
    M[j*FF + f] = acc * 0.0625f;
}

// ---------------- K0b: tiled transpose dst[C][R] = src[R][C]^T ----------------
__global__ __launch_bounds__(256) void k_transpose(const float* __restrict__ src,
                                                   float* __restrict__ dst,
                                                   int R, int C) {
    __shared__ float t[32][33];
    int c0 = blockIdx.x * 32, r0 = blockIdx.y * 32;
    int tx = threadIdx.x & 31, ty = threadIdx.x >> 5;
    #pragma unroll
    for (int i = 0; i < 32; i += 8)
        t[ty + i][tx] = src[(size_t)(r0 + ty + i) * C + c0 + tx];
    __syncthreads();
    #pragma unroll
    for (int i = 0; i < 32; i += 8)
        dst[(size_t)(c0 + ty + i) * R + r0 + tx] = t[tx][ty + i];
}

// ---------------- K1: slots0 ; qkg2/GB for iter 0 ----------------
// qkg2[b][j][s][t] = ln_in_g[4j+t] * qk[s][4j+t]   (packed per f4-group)
// GB[b][0..7] = Gq[s] = sum_f g*qk ; GB[b][8..15] = Bq[s] = sum_f b*qk
__global__ __launch_bounds__(256) void k_init(const float* __restrict__ noise,
                                              const float* __restrict__ mu,
                                              const float* __restrict__ lsig,
                                              const float* __restrict__ gs,
                                              const float* __restrict__ bs,
                                              const float* __restrict__ M,
                                              const float* __restrict__ g_in,
                                              const float* __restrict__ b_in,
                                              float* __restrict__ slots,
                                              float* __restrict__ qkg2,
                                              float* __restrict__ GB) {
    int b = blockIdx.x, tid = threadIdx.x, wave = tid >> 6;
    __shared__ float sn[SS*DD];
    __shared__ float redA[4], redB[4];
    __shared__ float red2[4][16];
    float ps = 0.f, pq = 0.f;
    float mud = mu[tid];
    float sgd = expf(lsig[tid]);
    #pragma unroll
    for (int s = 0; s < SS; ++s) {
        int idx = s*DD + tid;
        float v = mud + sgd * noise[b*(SS*DD) + idx];
        slots[(size_t)b*(SS*DD) + idx] = v;
        sn[idx] = v;
        ps += v; pq += v*v;
    }
    #pragma unroll
    for (int m = 1; m < 64; m <<= 1) { ps += __shfl_xor(ps, m); pq += __shfl_xor(pq, m); }
    if ((tid & 63) == 0) { redA[tid>>6] = ps; redB[tid>>6] = pq; }
    __syncthreads();
    float S_ = redA[0]+redA[1]+redA[2]+redA[3];
    float Q_ = redB[0]+redB[1]+redB[2]+redB[3];
    float mean = S_ * (1.f/2048.f);
    float var  = Q_ * (1.f/2048.f) - mean*mean;
    float rinv = rsqrtf(var + 1e-5f);
    #pragma unroll
    for (int s = 0; s < SS; ++s) {
        int idx = s*DD + tid;
        sn[idx] = (sn[idx]-mean)*rinv*gs[idx] + bs[idx];
    }
    __syncthreads();
    float acc[8] = {0,0,0,0,0,0,0,0};
    for (int j = 0; j < DD; ++j) {
        float mv = M[j*FF + tid];
        #pragma unroll
        for (int s = 0; s < SS; ++s) acc[s] += sn[s*DD + j] * mv;
    }
    // pack qkg2 + reduce Gq/Bq
    float gv = g_in[tid], bv = b_in[tid];
    float pg[8], pb[8];
    #pragma unroll
    for (int s = 0; s < SS; ++s) {
        float gq = acc[s]*gv;
        qkg2[((size_t)b*64 + (tid>>2))*32 + s*4 + (tid&3)] = gq;
        pg[s] = gq; pb[s] = acc[s]*bv;
    }
    #pragma unroll
    for (int s = 0; s < SS; ++s) {
        pg[s] = waveAllSum(pg[s]);
        pb[s] = waveAllSum(pb[s]);
    }
    if ((tid & 63) == 0) {
        #pragma unroll
        for (int s = 0; s < SS; ++s) { red2[wave][s*2] = pg[s]; red2[wave][s*2+1] = pb[s]; }
    }
    __syncthreads();
    if (tid < 16) {
        int which = tid >> 3, s = tid & 7;
        float t = red2[0][s*2+which] + red2[1][s*2+which] + red2[2][s*2+which] + red2[3][s*2+which];
        GB[b*16 + which*8 + s] = t;
    }
}

// ---------------- K2: two-phase attention pass (no per-row butterflies) ----------------
__global__ __launch_bounds__(256, 4) void k_attn(const float* __restrict__ x,
                                                 const float* __restrict__ ln_g,
                                                 const float* __restrict__ ln_b,
                                                 const float* __restrict__ qkg2,
                                                 const float* __restrict__ GB,
                                                 float* __restrict__ u_part,
                                                 float* __restrict__ sum_part) {
    int bid = blockIdx.x;
    int b = bid >> 4, c = bid & 15;
    int tid = threadIdx.x, wave = tid >> 6, lane = tid & 63;
    int row0 = c*256 + wave*64;           // this wave's 64-row tile
    const float* xb = x + (size_t)b * NN * FF;

    __shared__ float a_l[256*8];          // aa = a*rinv, per row, 8 slots
    __shared__ float u_l[SS*FF];
    __shared__ float wsum[4][8];
    __shared__ float wA0[4][8];

    // uniform per-batch constants
    const float4* gbp = (const float4*)(GB + b*16);
    float4 Gq03 = gbp[0], Gq47 = gbp[1], Bq03 = gbp[2], Bq47 = gbp[3];

    // ---- phase A: lane = row; serial in-lane reduction over f ----
    int row = row0 + lane;
    const float4* xr = (const float4*)(xb + (size_t)row * FF);
    const float4* qg = (const float4*)(qkg2 + (size_t)b * 2048);

    float dot0=0,dot1=0,dot2=0,dot3=0,dot4=0,dot5=0,dot6=0,dot7=0;
    float sx = 0.f, sxx = 0.f;
    for (int j = 0; j < 64; ++j) {
        float4 x4 = xr[j];
        const float4* q = qg + j*8;
        float4 q0=q[0], q1=q[1], q2=q[2], q3=q[3], q4=q[4], q5=q[5], q6=q[6], q7=q[7];
        sx  += x4.x + x4.y + x4.z + x4.w;
        sxx += x4.x*x4.x + x4.y*x4.y + x4.z*x4.z + x4.w*x4.w;
        dot0 += x4.x*q0.x + x4.y*q0.y + x4.z*q0.z + x4.w*q0.w;
        dot1 += x4.x*q1.x + x4.y*q1.y + x4.z*q1.z + x4.w*q1.w;
        dot2 += x4.x*q2.x + x4.y*q2.y + x4.z*q2.z + x4.w*q2.w;
        dot3 += x4.x*q3.x + x4.y*q3.y + x4.z*q3.z + x4.w*q3.w;
        dot4 += x4.x*q4.x + x4.y*q4.y + x4.z*q4.z + x4.w*q4.w;
        dot5 += x4.x*q5.x + x4.y*q5.y + x4.z*q5.z + x4.w*q5.w;
        dot6 += x4.x*q6.x + x4.y*q6.y + x4.z*q6.z + x4.w*q6.w;
        dot7 += x4.x*q7.x + x4.y*q7.y + x4.z*q7.z + x4.w*q7.w;
    }
    float mean = sx * (1.f/256.f);
    float var  = sxx * (1.f/256.f) - mean*mean;
    float rinv = rsqrtf(var + 1e-5f);
    float c0   = -mean * rinv;

    float lg[8];
    lg[0] = rinv*dot0 + c0*Gq03.x + Bq03.x;
    lg[1] = rinv*dot1 + c0*Gq03.y + Bq03.y;
    lg[2] = rinv*dot2 + c0*Gq03.z + Bq03.z;
    lg[3] = rinv*dot3 + c0*Gq03.w + Bq03.w;
    lg[4] = rinv*dot4 + c0*Gq47.x + Bq47.x;
    lg[5] = rinv*dot5 + c0*Gq47.y + Bq47.y;
    lg[6] = rinv*dot6 + c0*Gq47.z + Bq47.z;
    lg[7] = rinv*dot7 + c0*Gq47.w + Bq47.w;
    float mx = fmaxf(fmaxf(fmaxf(lg[0],lg[1]), fmaxf(lg[2],lg[3])),
                     fmaxf(fmaxf(lg[4],lg[5]), fmaxf(lg[6],lg[7])));
    float e[8]; float T = 0.f;
    #pragma unroll
    for (int s = 0; s < 8; ++s) { e[s] = __expf(lg[s]-mx); T += e[s]; }
    float inv = 1.0f / T;
    float a_[8], SAl[8], A0l[8];
    #pragma unroll
    for (int s = 0; s < 8; ++s) {
        float a = e[s]*inv + EPSV;
        a_[s] = a * rinv;          // aa for phase B
        SAl[s] = a;
        A0l[s] = a * c0;
    }
    // stage aa to wave-private LDS (wave-coherent, no barrier needed)
    *(float4*)&a_l[(wave*64+lane)*8]     = make_float4(a_[0],a_[1],a_[2],a_[3]);
    *(float4*)&a_l[(wave*64+lane)*8 + 4] = make_float4(a_[4],a_[5],a_[6],a_[7]);

    // ---- phase B: lane = f-slice; coalesced accumulate over the same 64 rows ----
    float u[8][4];
    #pragma unroll
    for (int s = 0; s < 8; ++s) { u[s][0]=0.f; u[s][1]=0.f; u[s][2]=0.f; u[s][3]=0.f; }
    const float4* xc = (const float4*)(xb + (size_t)row0 * FF);
    for (int r2 = 0; r2 < 64; ++r2) {
        float4 x4 = xc[r2*64 + lane];
        float4 a03 = *(const float4*)&a_l[(wave*64+r2)*8];
        float4 a47 = *(const float4*)&a_l[(wave*64+r2)*8 + 4];
        u[0][0] += a03.x*x4.x; u[0][1] += a03.x*x4.y; u[0][2] += a03.x*x4.z; u[0][3] += a03.x*x4.w;
        u[1][0] += a03.y*x4.x; u[1][1] += a03.y*x4.y; u[1][2] += a03.y*x4.z; u[1][3] += a03.y*x4.w;
        u[2][0] += a03.z*x4.x; u[2][1] += a03.z*x4.y; u[2][2] += a03.z*x4.z; u[2][3] += a03.z*x4.w;
        u[3][0] += a03.w*x4.x; u[3][1] += a03.w*x4.y; u[3][2] += a03.w*x4.z; u[3][3] += a03.w*x4.w;
        u[4][0] += a47.x*x4.x; u[4][1] += a47.x*x4.y; u[4][2] += a47.x*x4.z; u[4][3] += a47.x*x4.w;
        u[5][0] += a47.y*x4.x; u[5][1] += a47.y*x4.y; u[5][2] += a47.y*x4.z; u[5][3] += a47.y*x4.w;
        u[6][0] += a47.z*x4.x; u[6][1] += a47.z*x4.y; u[6][2] += a47.z*x4.z; u[6][3] += a47.z*x4.w;
        u[7][0] += a47.w*x4.x; u[7][1] += a47.w*x4.y; u[7][2] += a47.w*x4.z; u[7][3] += a47.w*x4.w;
    }

    // tile-level sums (once per 64 rows instead of per row)
    float SA[8], A0[8];
    #pragma unroll
    for (int s = 0; s < 8; ++s) { SA[s] = waveAllSum(SAl[s]); A0[s] = waveAllSum(A0l[s]); }
    if (lane == 0) {
        #pragma unroll
        for (int s = 0; s < 8; ++s) { wsum[wave][s] = SA[s]; wA0[wave][s] = A0[s]; }
    }

    // cross-wave combine of u (A1 term)
    const int f0 = lane * 4;
    for (int w = 0; w < 4; ++w) {
        if (wave == w) {
            #pragma unroll
            for (int s = 0; s < SS; ++s) {
                float4* p = (float4*)&u_l[s*FF + f0];
                if (w == 0) *p = make_float4(u[s][0], u[s][1], u[s][2], u[s][3]);
                else { float4 o = *p; *p = make_float4(o.x+u[s][0], o.y+u[s][1], o.z+u[s][2], o.w+u[s][3]); }
            }
        }
        __syncthreads();
    }

    // final write: u_part = g*(A1 + A0) + b*SA
    float* up = u_part + (size_t)bid * (SS*FF);
    for (int k = tid; k < (SS*FF)/4; k += 256) {
        int s = k >> 6; int f = (k & 63) << 2;
        float4 uv = ((const float4*)u_l)[k];
        float4 g4 = *(const float4*)&ln_g[f];
        float4 b4 = *(const float4*)&ln_b[f];
        float A0t = wA0[0][s]+wA0[1][s]+wA0[2][s]+wA0[3][s];
        float SAt = wsum[0][s]+wsum[1][s]+wsum[2][s]+wsum[3][s];
        float4 o;
        o.x = g4.x*(uv.x + A0t) + b4.x*SAt;
        o.y = g4.y*(uv.y + A0t) + b4.y*SAt;
        o.z = g4.z*(uv.z + A0t) + b4.z*SAt;
        o.w = g4.w*(uv.w + A0t) + b4.w*SAt;
        ((float4*)up)[k] = o;
    }
    if (tid < 8)
        sum_part[bid*8 + tid] = wsum[0][tid]+wsum[1][tid]+wsum[2][tid]+wsum[3][tid];
}

// ---------------- K3: updates -> GRU -> LN_m -> MLP (+ next-iter qkg2/GB) ----------------
template<bool LAST>
__global__ __launch_bounds__(512, 2) void k_update(const float* __restrict__ u_part,
                                                   const float* __restrict__ sum_part,
                                                   float* __restrict__ slots,
                                                   const float* __restrict__ WvT,
                                                   const float* __restrict__ WihT,
                                                   const float* __restrict__ WhhT,
                                                   const float* __restrict__ b_ih,
                                                   const float* __restrict__ b_hh,
                                                   const float* __restrict__ gm,
                                                   const float* __restrict__ bm,
                                                   const float* __restrict__ W1T,
                                                   const float* __restrict__ b1v,
                                                   const float* __restrict__ W2T,
                                                   const float* __restrict__ b2v,
                                                   const float* __restrict__ gs,
                                                   const float* __restrict__ bs,
                                                   const float* __restrict__ M,
                                                   const float* __restrict__ g_in,
                                                   const float* __restrict__ b_in,
                                                   float* __restrict__ qkg2,
                                                   float* __restrict__ GB,
                                                   float* __restrict__ outp) {
    int b = blockIdx.x, tid = threadIdx.x;
    __shared__ float u_l[2048], sl_l[2048], upd_l[2048], hn_l[2048], ml_l[2048];
    __shared__ float hid_l[SS*HH];
    __shared__ float ssinv[8];
    __shared__ float redA[8], redB[8];
    __shared__ float red2[8][8];

    { // reduce CPB partials + load slots_prev (512 float4 = 2048)
        float4 acc = make_float4(0,0,0,0);
        const float4* upp = (const float4*)(u_part + (size_t)b*CPB*2048);
        for (int p = 0; p < CPB; ++p) {
            float4 v = upp[p*512 + tid];
            acc.x += v.x; acc.y += v.y; acc.z += v.z; acc.w += v.w;
        }
        ((float4*)u_l)[tid] = acc;
        ((float4*)sl_l)[tid] = ((const float4*)(slots + (size_t)b*2048))[tid];
    }
    if (tid < 8) {
        float s0_ = 0.f;
        for (int p = 0; p < CPB; ++p) s0_ += sum_part[(b*CPB + p)*8 + tid];
        ssinv[tid] = 1.0f / s0_;
    }
    __syncthreads();

    int d = tid & 255, sh = tid >> 8;   // sh in {0,1}: 4 slots each

    { // updates[s][d] = (sum_f u[s][f] WvT[f][d]) * ssinv[s]
        float a0=0.f,a1=0.f,a2=0.f,a3=0.f;
        const float4* uv = (const float4*)u_l;
        for (int f4 = 0; f4 < 64; ++f4) {
            float4 c0 = uv[(sh*4+0)*64 + f4];
            float4 c1 = uv[(sh*4+1)*64 + f4];
            float4 c2 = uv[(sh*4+2)*64 + f4];
            float4 c3 = uv[(sh*4+3)*64 + f4];
            const float* wb = WvT + (f4*4)*DD + d;
            float w0 = wb[0], w1 = wb[DD], w2 = wb[2*DD], w3 = wb[3*DD];
            a0 += c0.x*w0 + c0.y*w1 + c0.z*w2 + c0.w*w3;
            a1 += c1.x*w0 + c1.y*w1 + c1.z*w2 + c1.w*w3;
            a2 += c2.x*w0 + c2.y*w1 + c2.z*w2 + c2.w*w3;
            a3 += c3.x*w0 + c3.y*w1 + c3.z*w2 + c3.w*w3;
        }
        upd_l[(sh*4+0)*DD + d] = a0 * ssinv[sh*4+0];
        upd_l[(sh*4+1)*DD + d] = a1 * ssinv[sh*4+1];
        upd_l[(sh*4+2)*DD + d] = a2 * ssinv[sh*4+2];
        upd_l[(sh*4+3)*DD + d] = a3 * ssinv[sh*4+3];
    }
    __syncthreads();

    float hnew[4];
    { // GRU: 4 slots per thread, 24 FMA per weight-sextet
        float aR[4]={0,0,0,0}, aZ[4]={0,0,0,0}, aN[4]={0,0,0,0};
        float hR[4]={0,0,0,0}, hZ[4]={0,0,0,0}, hN[4]={0,0,0,0};
        const float4* updv = (const float4*)upd_l;
        const float4* slv  = (const float4*)sl_l;
        for (int f4 = 0; f4 < 64; ++f4) {
            float4 u0 = updv[(sh*4+0)*64 + f4];
            float4 u1 = updv[(sh*4+1)*64 + f4];
            float4 u2 = updv[(sh*4+2)*64 + f4];
            float4 u3 = updv[(sh*4+3)*64 + f4];
            float4 p0 = slv[(sh*4+0)*64 + f4];
            float4 p1 = slv[(sh*4+1)*64 + f4];
            float4 p2 = slv[(sh*4+2)*64 + f4];
            float4 p3 = slv[(sh*4+3)*64 + f4];
            const float* wb = WihT + (size_t)(f4*4)*768 + d;
            const float* vb = WhhT + (size_t)(f4*4)*768 + d;
#define GS(J, C0, C1, C2, C3, P0, P1, P2, P3) { \
            float wr = wb[J*768], wz = wb[J*768+256], wn = wb[J*768+512]; \
            float vr = vb[J*768], vz = vb[J*768+256], vn = vb[J*768+512]; \
            aR[0]+=C0*wr; aZ[0]+=C0*wz; aN[0]+=C0*wn; hR[0]+=P0*vr; hZ[0]+=P0*vz; hN[0]+=P0*vn; \
            aR[1]+=C1*wr; aZ[1]+=C1*wz; aN[1]+=C1*wn; hR[1]+=P1*vr; hZ[1]+=P1*vz; hN[1]+=P1*vn; \
            aR[2]+=C2*wr; aZ[2]+=C2*wz; aN[2]+=C2*wn; hR[2]+=P2*vr; hZ[2]+=P2*vz; hN[2]+=P2*vn; \
            aR[3]+=C3*wr; aZ[3]+=C3*wz; aN[3]+=C3*wn; hR[3]+=P3*vr; hZ[3]+=P3*vz; hN[3]+=P3*vn; }
            GS(0, u0.x, u1.x, u2.x, u3.x, p0.x, p1.x, p2.x, p3.x)
            GS(1, u0.y, u1.y, u2.y, u3.y, p0.y, p1.y, p2.y, p3.y)
            GS(2, u0.z, u1.z, u2.z, u3.z, p0.z, p1.z, p2.z, p3.z)
            GS(3, u0.w, u1.w, u2.w, u3.w, p0.w, p1.w, p2.w, p3.w)
#undef GS
        }
        float bir = b_ih[d], biz = b_ih[256+d], bin_ = b_ih[512+d];
        float bhr = b_hh[d], bhz = b_hh[256+d], bhn  = b_hh[512+d];
        #pragma unroll
        for (int k = 0; k < 4; ++k) {
            float r  = 1.f/(1.f + __expf(-(aR[k]+bir + hR[k]+bhr)));
            float z  = 1.f/(1.f + __expf(-(aZ[k]+biz + hZ[k]+bhz)));
            float nn = tanhf(aN[k]+bin_ + r*(hN[k]+bhn));
            float hp = sl_l[(sh*4+k)*DD + d];
            hnew[k] = (1.f - z)*nn + z*hp;
            hn_l[(sh*4+k)*DD + d] = hnew[k];
        }
    }
    __syncthreads();

    float mean, rinv;
    { // LN_m stats over 2048 (8 waves)
        float ps = hnew[0]+hnew[1]+hnew[2]+hnew[3];
        float pq = hnew[0]*hnew[0]+hnew[1]*hnew[1]+hnew[2]*hnew[2]+hnew[3]*hnew[3];
        #pragma unroll
        for (int m = 1; m < 64; m <<= 1) { ps += __shfl_xor(ps, m); pq += __shfl_xor(pq, m); }
        if ((tid & 63) == 0) { redA[tid>>6] = ps; redB[tid>>6] = pq; }
        __syncthreads();
        float S_ = 0.f, Q_ = 0.f;
        #pragma unroll
        for (int w = 0; w < 8; ++w) { S_ += redA[w]; Q_ += redB[w]; }
        mean = S_ * (1.f/2048.f);
        float var = Q_ * (1.f/2048.f) - mean*mean;
        rinv = rsqrtf(var + 1e-5f);
        __syncthreads();
    }
    { // ml = LN_m(hnew)*gm + bm
        int k4 = tid*4;
        float4 h4 = *(const float4*)&hn_l[k4];
        float4 g4 = *(const float4*)&gm[k4];
        float4 bb = *(const float4*)&bm[k4];
        ml_l[k4+0] = (h4.x-mean)*rinv*g4.x + bb.x;
        ml_l[k4+1] = (h4.y-mean)*rinv*g4.y + bb.y;
        ml_l[k4+2] = (h4.z-mean)*rinv*g4.z + bb.z;
        ml_l[k4+3] = (h4.w-mean)*rinv*g4.w + bb.w;
    }
    __syncthreads();

    { // MLP1: h = tid (512), all 8 slots -> 8x weight reuse
        int h = tid;
        float acc[8] = {0,0,0,0,0,0,0,0};
        const float4* mlv = (const float4*)ml_l;
        for (int d4 = 0; d4 < 64; ++d4) {
            const float* wb = W1T + (size_t)(d4*4)*HH + h;
            float w0 = wb[0], w1 = wb[HH], w2 = wb[2*HH], w3 = wb[3*HH];
            #pragma unroll
            for (int s = 0; s < 8; ++s) {
                float4 m = mlv[s*64 + d4];
                acc[s] += m.x*w0 + m.y*w1 + m.z*w2 + m.w*w3;
            }
        }
        float bb1 = b1v[h];
        #pragma unroll
        for (int s = 0; s < 8; ++s) hid_l[s*HH + h] = fmaxf(acc[s] + bb1, 0.f);
    }
    __syncthreads();

    float outv[4];
    { // MLP2 + residual
        float a[4] = {0,0,0,0};
        const float4* hv = (const float4*)hid_l;
        for (int h4 = 0; h4 < 128; ++h4) {
            const float* wb = W2T + (size_t)(h4*4)*DD + d;
            float w0 = wb[0], w1 = wb[DD], w2 = wb[2*DD], w3 = wb[3*DD];
            #pragma unroll
            for (int k = 0; k < 4; ++k) {
                float4 q = hv[(sh*4+k)*128 + h4];
                a[k] += q.x*w0 + q.y*w1 + q.z*w2 + q.w*w3;
            }
        }
        float bb2 = b2v[d];
        #pragma unroll
        for (int k = 0; k < 4; ++k) outv[k] = hn_l[(sh*4+k)*DD + d] + a[k] + bb2;
    }

    if (LAST) {
        #pragma unroll
        for (int k = 0; k < 4; ++k)
            outp[((size_t)b*SS + sh*4+k)*DD + d] = outv[k];
        return;
    }

    #pragma unroll
    for (int k = 0; k < 4; ++k) {
        slots[(size_t)b*2048 + (sh*4+k)*DD + d] = outv[k];
        upd_l[(sh*4+k)*DD + d] = outv[k];   // stage new slots for LN_s
    }
    float mean2, rinv2;
    { // LN_s stats of new slots
        float ps = outv[0]+outv[1]+outv[2]+outv[3];
        float pq = outv[0]*outv[0]+outv[1]*outv[1]+outv[2]*outv[2]+outv[3]*outv[3];
        #pragma unroll
        for (int m = 1; m < 64; m <<= 1) { ps += __shfl_xor(ps, m); pq += __shfl_xor(pq, m); }
        if ((tid & 63) == 0) { redA[tid>>6] = ps; redB[tid>>6] = pq; }
        __syncthreads();
        float S_ = 0.f, Q_ = 0.f;
        #pragma unroll
        for (int w = 0; w < 8; ++w) { S_ += redA[w]; Q_ += redB[w]; }
        mean2 = S_ * (1.f/2048.f);
        float var = Q_ * (1.f/2048.f) - mean2*mean2;
        rinv2 = rsqrtf(var + 1e-5f);
    }
    { // sn into ml_l
        int k4 = tid*4;
        float4 sv = *(const float4*)&upd_l[k4];
        float4 g4 = *(const float4*)&gs[k4];
        float4 bb = *(const float4*)&bs[k4];
        ml_l[k4+0] = (sv.x-mean2)*rinv2*g4.x + bb.x;
        ml_l[k4+1] = (sv.y-mean2)*rinv2*g4.y + bb.y;
        ml_l[k4+2] = (sv.z-mean2)*rinv2*g4.z + bb.z;
        ml_l[k4+3] = (sv.w-mean2)*rinv2*g4.w + bb.w;
    }
    __syncthreads();
    { // qk_next = sn @ M ; pack qkg2 + reduce Gq/Bq
        float a[4] = {0,0,0,0};
        const float4* sv = (const float4*)ml_l;
        for (int j4 = 0; j4 < 64; ++j4) {
            const float* mb = M + (size_t)(j4*4)*FF + d;
            float w0 = mb[0], w1 = mb[FF], w2 = mb[2*FF], w3 = mb[3*FF];
            #pragma unroll
            for (int k = 0; k < 4; ++k) {
                float4 c = sv[(sh*4+k)*64 + j4];
                a[k] += c.x*w0 + c.y*w1 + c.z*w2 + c.w*w3;
            }
        }
        float gv = g_in[d], bv = b_in[d];
        float pg[4], pb[4];
        #pragma unroll
        for (int k = 0; k < 4; ++k) {
            int s = sh*4 + k;
            float gq = a[k]*gv;
            qkg2[((size_t)b*64 + (d>>2))*32 + s*4 + (d&3)] = gq;
            pg[k] = gq; pb[k] = a[k]*bv;
        }
        int wave = tid >> 6;
        #pragma unroll
        for (int k = 0; k < 4; ++k) { pg[k] = waveAllSum(pg[k]); pb[k] = waveAllSum(pb[k]); }
        if ((tid & 63) == 0) {
            #pragma unroll
            for (int k = 0; k < 4; ++k) { red2[wave][k*2] = pg[k]; red2[wave][k*2+1] = pb[k]; }
        }
        __syncthreads();
        if (tid < 16) {
            int which = tid >> 3, s = tid & 7;
            int w0 = (s >> 2) * 4, k = s & 3;
            float t = red2[w0][k*2+which] + red2[w0+1][k*2+which]
                    + red2[w0+2][k*2+which] + red2[w0+3][k*2+which];
            GB[b*16 + which*8 + s] = t;
        }
    }
}

// ---------------- launch ----------------
extern "C" void kernel_launch(void* const* d_in, const int* in_sizes, int n_in,
                              void* d_out, int out_size, void* d_ws, size_t ws_size,
                              hipStream_t stream) {
    const float* x        = (const float*)d_in[0];
    const float* noise    = (const float*)d_in[1];
    const float* ln_in_g  = (const float*)d_in[2];
    const float* ln_in_b  = (const float*)d_in[3];
    const float* ln_s_g   = (const float*)d_in[4];
    const float* ln_s_b   = (const float*)d_in[5];
    const float* ln_m_g   = (const float*)d_in[6];
    const float* ln_m_b   = (const float*)d_in[7];
    const float* slots_mu = (const float*)d_in[8];
    const float* slots_ls = (const float*)d_in[9];
    const float* Wq       = (const float*)d_in[10];
    const float* Wk       = (const float*)d_in[11];
    const float* Wv       = (const float*)d_in[12];
    const float* W_ih     = (const float*)d_in[13];
    const float* W_hh     = (const float*)d_in[14];
    const float* b_ih     = (const float*)d_in[15];
    const float* b_hh     = (const float*)d_in[16];
    const float* W1       = (const float*)d_in[17];
    const float* b1       = (const float*)d_in[18];
    const float* W2       = (const float*)d_in[19];
    const float* b2       = (const float*)d_in[20];

    float* ws       = (float*)d_ws;
    float* M        = ws;                          // 65536
    float* qkg2     = M + 65536;                   // B*2048 = 131072
    float* GB       = qkg2 + 131072;               // B*16 = 1024
    float* slots    = GB + 1024;                   // 131072
    float* WvT      = slots + 131072;              // 65536
    float* WihT     = WvT + 65536;                 // 196608
    float* WhhT     = WihT + 196608;               // 196608
    float* W1T      = WhhT + 196608;               // 131072
    float* W2T      = W1T + 131072;                // 131072
    float* u_part   = W2T + 131072;                // NBLK*2048 = 2097152
    float* sum_part = u_part + (size_t)NBLK*2048;  // 8192
    float* outp     = (float*)d_out;

    k_precompute_M<<<256, 256, 0, stream>>>(Wq, Wk, M);
    k_transpose<<<dim3(256/32, 256/32), 256, 0, stream>>>(Wv,   WvT,  256, 256);
    k_transpose<<<dim3(256/32, 768/32), 256, 0, stream>>>(W_ih, WihT, 768, 256);
    k_transpose<<<dim3(256/32, 768/32), 256, 0, stream>>>(W_hh, WhhT, 768, 256);
    k_transpose<<<dim3(256/32, 512/32), 256, 0, stream>>>(W1,   W1T,  512, 256);
    k_transpose<<<dim3(512/32, 256/32), 256, 0, stream>>>(W2,   W2T,  256, 512);
    k_init<<<BB, 256, 0, stream>>>(noise, slots_mu, slots_ls, ln_s_g, ln_s_b, M,
                                   ln_in_g, ln_in_b, slots, qkg2, GB);
    for (int it = 0; it < 3; ++it) {
        k_attn<<<NBLK, 256, 0, stream>>>(x, ln_in_g, ln_in_b, qkg2, GB, u_part, sum_part);
        if (it < 2) {
            k_update<false><<<BB, 512, 0, stream>>>(u_part, sum_part, slots, WvT, WihT, WhhT,
                b_ih, b_hh, ln_m_g, ln_m_b, W1T, b1, W2T, b2, ln_s_g, ln_s_b, M,
                ln_in_g, ln_in_b, qkg2, GB, outp);
        } else {
            k_update<true><<<BB, 512, 0, stream>>>(u_part, sum_part, slots, WvT, WihT, WhhT,
                b_ih, b_hh, ln_m_g, ln_m_b, W1T, b1, W2T, b2, ln_s_g, ln_s_b, M,
                ln_in_g, ln_in_b, qkg2, GB, outp);
        }
    }
}